// Round 8
// baseline (187.915 us; speedup 1.0000x reference)
//
#include <hip/hip_runtime.h>

#define NN 50000
#define NE 600000
#define DI 128
#define DH 16
#define DC 8
#define CAP 64     // ELL capacity; deg ~ Binomial(600K,1/50K)≈Poisson(12), P(deg>64) ~ e^-55
#define NB 196     // ceil(NN/256)
#define NBL 782    // ceil(NN*4/256) blocks for fused layers kernel

// ---- agent-scope grid barrier (all NBL blocks co-resident: 3128 waves << 8192) ----
__device__ __forceinline__ void grid_barrier_all(int* cnt, int* gen, int nblocks)
{
    __syncthreads();
    if (threadIdx.x == 0) {
        int g = __hip_atomic_load(gen, __ATOMIC_RELAXED, __HIP_MEMORY_SCOPE_AGENT);
        int c = __hip_atomic_fetch_add(cnt, 1, __ATOMIC_ACQ_REL, __HIP_MEMORY_SCOPE_AGENT);
        if (c == nblocks - 1) {
            __hip_atomic_store(cnt, 0, __ATOMIC_RELAXED, __HIP_MEMORY_SCOPE_AGENT);
            __hip_atomic_store(gen, g + 1, __ATOMIC_RELEASE, __HIP_MEMORY_SCOPE_AGENT);
        } else {
            while (__hip_atomic_load(gen, __ATOMIC_ACQUIRE, __HIP_MEMORY_SCOPE_AGENT) == g)
                __builtin_amdgcn_s_sleep(2);
        }
    }
    __syncthreads();
}

// ---------------- K0: xl = x @ W1l, xr = x @ W1r (+ zero cnt, bar) ----------------
__global__ __launch_bounds__(256) void k_gemm1(
    const float* __restrict__ x,
    const float* __restrict__ W1l,
    const float* __restrict__ W1r,
    float* __restrict__ xl,
    float* __restrict__ xr,
    int* __restrict__ cnt,
    int* __restrict__ bar)
{
    int n = blockIdx.x * 256 + threadIdx.x;
    if (n < NN) cnt[n] = 0;
    if (blockIdx.x == 0 && threadIdx.x < 2) bar[threadIdx.x] = 0;

    __shared__ float Wc[DI][32];   // [k][j]: j<16 -> W1l, j>=16 -> W1r
    for (int i = threadIdx.x; i < DI * DH; i += 256) {
        int k = i >> 4, j = i & 15;
        Wc[k][j]      = W1l[i];
        Wc[k][j + 16] = W1r[i];
    }
    __syncthreads();
    if (n >= NN) return;

    float acc[32];
#pragma unroll
    for (int j = 0; j < 32; ++j) acc[j] = 0.f;

    const float4* xrow = (const float4*)(x + (size_t)n * DI);
#pragma unroll 2
    for (int k4 = 0; k4 < DI / 4; ++k4) {
        float4 xv = xrow[k4];
        float xa[4] = {xv.x, xv.y, xv.z, xv.w};
#pragma unroll
        for (int kk = 0; kk < 4; ++kk) {
            const float4* wr = (const float4*)(Wc[k4 * 4 + kk]);
#pragma unroll
            for (int j4 = 0; j4 < 8; ++j4) {
                float4 w = wr[j4];
                acc[j4 * 4 + 0] += xa[kk] * w.x;
                acc[j4 * 4 + 1] += xa[kk] * w.y;
                acc[j4 * 4 + 2] += xa[kk] * w.z;
                acc[j4 * 4 + 3] += xa[kk] * w.w;
            }
        }
    }
    float4* o1 = (float4*)(xl + (size_t)n * DH);
    float4* o2 = (float4*)(xr + (size_t)n * DH);
#pragma unroll
    for (int q = 0; q < 4; ++q) {
        o1[q] = make_float4(acc[q*4+0], acc[q*4+1], acc[q*4+2], acc[q*4+3]);
        o2[q] = make_float4(acc[16+q*4+0], acc[16+q*4+1], acc[16+q*4+2], acc[16+q*4+3]);
    }
}

// ---------------- K1: ELL fill, 2 edges/thread ----------------
__global__ __launch_bounds__(256) void k_fill_ell(
    const int* __restrict__ src, const int* __restrict__ dst,
    int* __restrict__ cnt, int* __restrict__ ell)
{
    int t = blockIdx.x * 256 + threadIdx.x;
    int e = t * 2;
    if (e >= NE) return;
    int2 d2 = *(const int2*)(dst + e);
    int2 s2 = *(const int2*)(src + e);
    int p0 = atomicAdd(&cnt[d2.x], 1);
    int p1 = atomicAdd(&cnt[d2.y], 1);
    if (p0 < CAP) ell[(size_t)d2.x * CAP + p0] = s2.x;
    if (p1 < CAP) ell[(size_t)d2.y * CAP + p1] = s2.y;
}

// ---------------- K2: fused layers: l1 (agg+relu+GEMM2) -> barrier -> l2 (agg+out) ----------------
__global__ __launch_bounds__(256) void k_layers(
    const int* __restrict__ cnt, const int* __restrict__ ell,
    const float* __restrict__ xl, const float* __restrict__ xr,
    const float* __restrict__ b1,
    const float* __restrict__ W2l, const float* __restrict__ W2r,
    const float* __restrict__ b2,
    float* __restrict__ zl, float* __restrict__ zr,
    float* __restrict__ out, int* __restrict__ bar)
{
    int t = blockIdx.x * 256 + threadIdx.x;

    // ================= phase 1: layer 1 (t < NN*4; thread = (node, quad)) =================
    if (t < NN * 4) {
        int n = t >> 2, q = t & 3;
        int len = min(cnt[n], CAP);
        const int* lst = ell + (size_t)n * CAP;
        const int q4 = q * 4;

        float4 a0 = make_float4(0.f,0.f,0.f,0.f), a1 = a0, a2 = a0, a3 = a0;
        int j = 0;
        for (; j + 4 <= len; j += 4) {
            int4 s4 = *(const int4*)(lst + j);          // 16B index preload
            float4 v0 = *(const float4*)(xl + s4.x * DH + q4);
            float4 v1 = *(const float4*)(xl + s4.y * DH + q4);
            float4 v2 = *(const float4*)(xl + s4.z * DH + q4);
            float4 v3 = *(const float4*)(xl + s4.w * DH + q4);
            a0.x += v0.x; a0.y += v0.y; a0.z += v0.z; a0.w += v0.w;
            a1.x += v1.x; a1.y += v1.y; a1.z += v1.z; a1.w += v1.w;
            a2.x += v2.x; a2.y += v2.y; a2.z += v2.z; a2.w += v2.w;
            a3.x += v3.x; a3.y += v3.y; a3.z += v3.z; a3.w += v3.w;
        }
        for (; j < len; ++j) {
            int s0 = lst[j];
            float4 v0 = *(const float4*)(xl + s0 * DH + q4);
            a0.x += v0.x; a0.y += v0.y; a0.z += v0.z; a0.w += v0.w;
        }
        a0.x += a1.x + a2.x + a3.x; a0.y += a1.y + a2.y + a3.y;
        a0.z += a1.z + a2.z + a3.z; a0.w += a1.w + a2.w + a3.w;

        float inv = 1.0f / fmaxf((float)len, 1.0f);
        float4 r  = *(const float4*)(xr + t * 4);       // == xr + n*16 + q*4
        float4 bb = *(const float4*)(b1 + q4);
        float4 hq;
        hq.x = fmaxf(a0.x * inv + bb.x + r.x, 0.f);
        hq.y = fmaxf(a0.y * inv + bb.y + r.y, 0.f);
        hq.z = fmaxf(a0.z * inv + bb.z + r.z, 0.f);
        hq.w = fmaxf(a0.w * inv + bb.w + r.w, 0.f);

        // exchange quads within the 4-lane node group
        float4 p1, p2, p3;
        p1.x = __shfl_xor(hq.x, 1, 64); p1.y = __shfl_xor(hq.y, 1, 64);
        p1.z = __shfl_xor(hq.z, 1, 64); p1.w = __shfl_xor(hq.w, 1, 64);
        p2.x = __shfl_xor(hq.x, 2, 64); p2.y = __shfl_xor(hq.y, 2, 64);
        p2.z = __shfl_xor(hq.z, 2, 64); p2.w = __shfl_xor(hq.w, 2, 64);
        p3.x = __shfl_xor(p1.x, 2, 64); p3.y = __shfl_xor(p1.y, 2, 64);
        p3.z = __shfl_xor(p1.z, 2, 64); p3.w = __shfl_xor(p1.w, 2, 64);
        float4 Q[4];
#pragma unroll
        for (int jq = 0; jq < 4; ++jq) {
            int d = jq ^ q;
            Q[jq] = (d == 0) ? hq : (d == 1) ? p1 : (d == 2) ? p2 : p3;
        }

        // layer-2 GEMM: thread computes concat outputs [q*4 .. q*4+4)
        const float* Wbase = (q < 2) ? (W2l + q * 4) : (W2r + (q - 2) * 4);
        float4 acc = make_float4(0.f, 0.f, 0.f, 0.f);
#pragma unroll
        for (int k = 0; k < DH; ++k) {
            float hk = (k < 4) ? ((const float*)&Q[0])[k & 3]
                     : (k < 8) ? ((const float*)&Q[1])[k & 3]
                     : (k < 12) ? ((const float*)&Q[2])[k & 3]
                     : ((const float*)&Q[3])[k & 3];
            float4 wv = *(const float4*)(Wbase + k * 8);
            acc.x += hk * wv.x; acc.y += hk * wv.y;
            acc.z += hk * wv.z; acc.w += hk * wv.w;
        }
        float* dstp = (q < 2) ? (zl + (size_t)n * DC + q * 4)
                              : (zr + (size_t)n * DC + (q - 2) * 4);
        *(float4*)dstp = acc;
    }

    grid_barrier_all(bar, bar + 1, NBL);

    // ================= phase 2: layer 2 (t < NN*2; thread = (node, half)) =================
    if (t < NN * 2) {
        int n = t >> 1, q = t & 1;
        int len = min(cnt[n], CAP);
        const int* lst = ell + (size_t)n * CAP;
        const int q4 = q * 4;

        float4 a0 = make_float4(0.f,0.f,0.f,0.f), a1 = a0, a2 = a0, a3 = a0;
        int j = 0;
        for (; j + 4 <= len; j += 4) {
            int4 s4 = *(const int4*)(lst + j);
            float4 v0 = *(const float4*)(zl + s4.x * DC + q4);
            float4 v1 = *(const float4*)(zl + s4.y * DC + q4);
            float4 v2 = *(const float4*)(zl + s4.z * DC + q4);
            float4 v3 = *(const float4*)(zl + s4.w * DC + q4);
            a0.x += v0.x; a0.y += v0.y; a0.z += v0.z; a0.w += v0.w;
            a1.x += v1.x; a1.y += v1.y; a1.z += v1.z; a1.w += v1.w;
            a2.x += v2.x; a2.y += v2.y; a2.z += v2.z; a2.w += v2.w;
            a3.x += v3.x; a3.y += v3.y; a3.z += v3.z; a3.w += v3.w;
        }
        for (; j < len; ++j) {
            int s0 = lst[j];
            float4 v0 = *(const float4*)(zl + s0 * DC + q4);
            a0.x += v0.x; a0.y += v0.y; a0.z += v0.z; a0.w += v0.w;
        }
        a0.x += a1.x + a2.x + a3.x; a0.y += a1.y + a2.y + a3.y;
        a0.z += a1.z + a2.z + a3.z; a0.w += a1.w + a2.w + a3.w;

        float inv = 1.0f / fmaxf((float)len, 1.0f);
        float4 r  = *(const float4*)(zr + t * 4);       // == zr + n*8 + q*4
        float4 bb = *(const float4*)(b2 + q4);
        float4 o;
        o.x = a0.x * inv + bb.x + r.x;
        o.y = a0.y * inv + bb.y + r.y;
        o.z = a0.z * inv + bb.z + r.z;
        o.w = a0.w * inv + bb.w + r.w;
        *(float4*)(out + t * 4) = o;
    }
}

extern "C" void kernel_launch(void* const* d_in, const int* in_sizes, int n_in,
                              void* d_out, int out_size, void* d_ws, size_t ws_size,
                              hipStream_t stream)
{
    const float* x   = (const float*)d_in[0];
    const int*   ei  = (const int*)d_in[1];
    const float* W1l = (const float*)d_in[2];
    const float* b1  = (const float*)d_in[3];
    const float* W1r = (const float*)d_in[4];
    const float* W2l = (const float*)d_in[5];
    const float* b2  = (const float*)d_in[6];
    const float* W2r = (const float*)d_in[7];
    float* out = (float*)d_out;

    const int* src = ei;
    const int* dst = ei + NE;

    // ---- workspace layout (floats first, 16B-aligned throughout) ----
    float* xl = (float*)d_ws;                      // NN*16
    float* xr = xl + (size_t)NN * DH;              // NN*16
    float* zl = xr + (size_t)NN * DH;              // NN*8
    float* zr = zl + (size_t)NN * DC;              // NN*8
    int* cnt  = (int*)(zr + (size_t)NN * DC);      // NN
    int* ell  = cnt + NN;                          // NN*CAP
    int* bar  = ell + (size_t)NN * CAP;            // 2
    // total ~22.6 MB

    k_gemm1   <<<NB, 256, 0, stream>>>(x, W1l, W1r, xl, xr, cnt, bar);
    k_fill_ell<<<(NE / 2 + 255) / 256, 256, 0, stream>>>(src, dst, cnt, ell);
    k_layers  <<<NBL, 256, 0, stream>>>(cnt, ell, xl, xr, b1, W2l, W2r, b2, zl, zr, out, bar);
}

// Round 9
// 77.375 us; speedup vs baseline: 2.4286x; 2.4286x over previous
//
#include <hip/hip_runtime.h>

#define NN 50000
#define NE 600000
#define DI 128
#define DH 16
#define DC 8
#define CAP 64     // ELL capacity; deg ~ Poisson(12), P(deg>64) < 1e-20
#define NB 196     // ceil(NN/256)

// ---------------- K0: xl = x @ W1l, xr = x @ W1r (+ zero cnt) ----------------
__global__ __launch_bounds__(256) void k_gemm1(
    const float* __restrict__ x,
    const float* __restrict__ W1l,
    const float* __restrict__ W1r,
    float* __restrict__ xl,
    float* __restrict__ xr,
    int* __restrict__ cnt)
{
    int n = blockIdx.x * 256 + threadIdx.x;
    if (n < NN) cnt[n] = 0;

    __shared__ float Wc[DI][32];   // [k][j]: j<16 -> W1l, j>=16 -> W1r
    for (int i = threadIdx.x; i < DI * DH; i += 256) {
        int k = i >> 4, j = i & 15;
        Wc[k][j]      = W1l[i];
        Wc[k][j + 16] = W1r[i];
    }
    __syncthreads();
    if (n >= NN) return;

    float acc[32];
#pragma unroll
    for (int j = 0; j < 32; ++j) acc[j] = 0.f;

    const float4* xrow = (const float4*)(x + (size_t)n * DI);
#pragma unroll 2
    for (int k4 = 0; k4 < DI / 4; ++k4) {
        float4 xv = xrow[k4];
        float xa[4] = {xv.x, xv.y, xv.z, xv.w};
#pragma unroll
        for (int kk = 0; kk < 4; ++kk) {
            const float4* wr = (const float4*)(Wc[k4 * 4 + kk]);
#pragma unroll
            for (int j4 = 0; j4 < 8; ++j4) {
                float4 w = wr[j4];
                acc[j4 * 4 + 0] += xa[kk] * w.x;
                acc[j4 * 4 + 1] += xa[kk] * w.y;
                acc[j4 * 4 + 2] += xa[kk] * w.z;
                acc[j4 * 4 + 3] += xa[kk] * w.w;
            }
        }
    }
    float4* o1 = (float4*)(xl + (size_t)n * DH);
    float4* o2 = (float4*)(xr + (size_t)n * DH);
#pragma unroll
    for (int q = 0; q < 4; ++q) {
        o1[q] = make_float4(acc[q*4+0], acc[q*4+1], acc[q*4+2], acc[q*4+3]);
        o2[q] = make_float4(acc[16+q*4+0], acc[16+q*4+1], acc[16+q*4+2], acc[16+q*4+3]);
    }
}

// ---------------- K1: ELL fill, 2 edges/thread ----------------
__global__ __launch_bounds__(256) void k_fill_ell(
    const int* __restrict__ src, const int* __restrict__ dst,
    int* __restrict__ cnt, int* __restrict__ ell)
{
    int e = (blockIdx.x * 256 + threadIdx.x) * 2;
    if (e >= NE) return;
    int2 d2 = *(const int2*)(dst + e);
    int2 s2 = *(const int2*)(src + e);
    int p0 = atomicAdd(&cnt[d2.x], 1);
    int p1 = atomicAdd(&cnt[d2.y], 1);
    if (p0 < CAP) ell[(size_t)d2.x * CAP + p0] = s2.x;
    if (p1 < CAP) ell[(size_t)d2.y * CAP + p1] = s2.y;
}

// ---------------- K2: agg1 (masked 8-deep) + relu + layer-2 GEMM (shfl) ----------------
__global__ __launch_bounds__(256) void k_l1(
    const int* __restrict__ cnt, const int* __restrict__ ell,
    const float* __restrict__ xl, const float* __restrict__ xr,
    const float* __restrict__ b1,
    const float* __restrict__ W2l, const float* __restrict__ W2r,
    float* __restrict__ zl, float* __restrict__ zr)
{
    int t = blockIdx.x * 256 + threadIdx.x;
    if (t >= NN * 4) return;
    int n = t >> 2, q = t & 3;
    const int q4 = q * 4;

    int len = min(cnt[n], CAP);
    const int* lst = ell + (size_t)n * CAP;

    float4 a0 = make_float4(0.f,0.f,0.f,0.f);
    for (int j = 0; j < len; j += 8) {
        // rows are CAP-padded: reading 8 ints at any j<len<=64 stays in-bounds (j<=56+7=63)
        int4 sA = *(const int4*)(lst + j);
        int4 sB = *(const int4*)(lst + j + 4);
        int i0 = (j + 0 < len) ? sA.x : 0;  float m0 = (j + 0 < len) ? 1.f : 0.f;
        int i1 = (j + 1 < len) ? sA.y : 0;  float m1 = (j + 1 < len) ? 1.f : 0.f;
        int i2 = (j + 2 < len) ? sA.z : 0;  float m2 = (j + 2 < len) ? 1.f : 0.f;
        int i3 = (j + 3 < len) ? sA.w : 0;  float m3 = (j + 3 < len) ? 1.f : 0.f;
        int i4 = (j + 4 < len) ? sB.x : 0;  float m4 = (j + 4 < len) ? 1.f : 0.f;
        int i5 = (j + 5 < len) ? sB.y : 0;  float m5 = (j + 5 < len) ? 1.f : 0.f;
        int i6 = (j + 6 < len) ? sB.z : 0;  float m6 = (j + 6 < len) ? 1.f : 0.f;
        int i7 = (j + 7 < len) ? sB.w : 0;  float m7 = (j + 7 < len) ? 1.f : 0.f;
        float4 v0 = *(const float4*)(xl + i0 * DH + q4);
        float4 v1 = *(const float4*)(xl + i1 * DH + q4);
        float4 v2 = *(const float4*)(xl + i2 * DH + q4);
        float4 v3 = *(const float4*)(xl + i3 * DH + q4);
        float4 v4 = *(const float4*)(xl + i4 * DH + q4);
        float4 v5 = *(const float4*)(xl + i5 * DH + q4);
        float4 v6 = *(const float4*)(xl + i6 * DH + q4);
        float4 v7 = *(const float4*)(xl + i7 * DH + q4);
        a0.x += v0.x*m0 + v1.x*m1 + v2.x*m2 + v3.x*m3 + v4.x*m4 + v5.x*m5 + v6.x*m6 + v7.x*m7;
        a0.y += v0.y*m0 + v1.y*m1 + v2.y*m2 + v3.y*m3 + v4.y*m4 + v5.y*m5 + v6.y*m6 + v7.y*m7;
        a0.z += v0.z*m0 + v1.z*m1 + v2.z*m2 + v3.z*m3 + v4.z*m4 + v5.z*m5 + v6.z*m6 + v7.z*m7;
        a0.w += v0.w*m0 + v1.w*m1 + v2.w*m2 + v3.w*m3 + v4.w*m4 + v5.w*m5 + v6.w*m6 + v7.w*m7;
    }

    float inv = 1.0f / fmaxf((float)len, 1.0f);
    float4 r  = *(const float4*)(xr + t * 4);       // == xr + n*16 + q*4
    float4 bb = *(const float4*)(b1 + q4);
    float4 hq;
    hq.x = fmaxf(a0.x * inv + bb.x + r.x, 0.f);
    hq.y = fmaxf(a0.y * inv + bb.y + r.y, 0.f);
    hq.z = fmaxf(a0.z * inv + bb.z + r.z, 0.f);
    hq.w = fmaxf(a0.w * inv + bb.w + r.w, 0.f);

    // exchange quads within the 4-lane node group
    float4 p1, p2, p3;
    p1.x = __shfl_xor(hq.x, 1, 64); p1.y = __shfl_xor(hq.y, 1, 64);
    p1.z = __shfl_xor(hq.z, 1, 64); p1.w = __shfl_xor(hq.w, 1, 64);
    p2.x = __shfl_xor(hq.x, 2, 64); p2.y = __shfl_xor(hq.y, 2, 64);
    p2.z = __shfl_xor(hq.z, 2, 64); p2.w = __shfl_xor(hq.w, 2, 64);
    p3.x = __shfl_xor(p1.x, 2, 64); p3.y = __shfl_xor(p1.y, 2, 64);
    p3.z = __shfl_xor(p1.z, 2, 64); p3.w = __shfl_xor(p1.w, 2, 64);
    float4 Q[4];
#pragma unroll
    for (int jq = 0; jq < 4; ++jq) {
        int d = jq ^ q;
        Q[jq] = (d == 0) ? hq : (d == 1) ? p1 : (d == 2) ? p2 : p3;
    }

    // layer-2 GEMM: thread computes concat outputs [q*4 .. q*4+4)
    const float* Wbase = (q < 2) ? (W2l + q * 4) : (W2r + (q - 2) * 4);
    float4 acc = make_float4(0.f, 0.f, 0.f, 0.f);
#pragma unroll
    for (int k = 0; k < DH; ++k) {
        float hk = (k < 4) ? ((const float*)&Q[0])[k & 3]
                 : (k < 8) ? ((const float*)&Q[1])[k & 3]
                 : (k < 12) ? ((const float*)&Q[2])[k & 3]
                 : ((const float*)&Q[3])[k & 3];
        float4 wv = *(const float4*)(Wbase + k * 8);
        acc.x += hk * wv.x; acc.y += hk * wv.y;
        acc.z += hk * wv.z; acc.w += hk * wv.w;
    }
    float* dstp = (q < 2) ? (zl + (size_t)n * DC + q * 4)
                          : (zr + (size_t)n * DC + (q - 2) * 4);
    *(float4*)dstp = acc;
}

// ---------------- K3: agg2 (masked 8-deep) + b2 + zr -> out ----------------
__global__ __launch_bounds__(256) void k_l2(
    const int* __restrict__ cnt, const int* __restrict__ ell,
    const float* __restrict__ zl, const float* __restrict__ zr,
    const float* __restrict__ b2, float* __restrict__ out)
{
    int t = blockIdx.x * 256 + threadIdx.x;
    if (t >= NN * 2) return;
    int n = t >> 1, q = t & 1;
    const int q4 = q * 4;
    int len = min(cnt[n], CAP);
    const int* lst = ell + (size_t)n * CAP;

    float4 a0 = make_float4(0.f,0.f,0.f,0.f);
    for (int j = 0; j < len; j += 8) {
        int4 sA = *(const int4*)(lst + j);
        int4 sB = *(const int4*)(lst + j + 4);
        int i0 = (j + 0 < len) ? sA.x : 0;  float m0 = (j + 0 < len) ? 1.f : 0.f;
        int i1 = (j + 1 < len) ? sA.y : 0;  float m1 = (j + 1 < len) ? 1.f : 0.f;
        int i2 = (j + 2 < len) ? sA.z : 0;  float m2 = (j + 2 < len) ? 1.f : 0.f;
        int i3 = (j + 3 < len) ? sA.w : 0;  float m3 = (j + 3 < len) ? 1.f : 0.f;
        int i4 = (j + 4 < len) ? sB.x : 0;  float m4 = (j + 4 < len) ? 1.f : 0.f;
        int i5 = (j + 5 < len) ? sB.y : 0;  float m5 = (j + 5 < len) ? 1.f : 0.f;
        int i6 = (j + 6 < len) ? sB.z : 0;  float m6 = (j + 6 < len) ? 1.f : 0.f;
        int i7 = (j + 7 < len) ? sB.w : 0;  float m7 = (j + 7 < len) ? 1.f : 0.f;
        float4 v0 = *(const float4*)(zl + i0 * DC + q4);
        float4 v1 = *(const float4*)(zl + i1 * DC + q4);
        float4 v2 = *(const float4*)(zl + i2 * DC + q4);
        float4 v3 = *(const float4*)(zl + i3 * DC + q4);
        float4 v4 = *(const float4*)(zl + i4 * DC + q4);
        float4 v5 = *(const float4*)(zl + i5 * DC + q4);
        float4 v6 = *(const float4*)(zl + i6 * DC + q4);
        float4 v7 = *(const float4*)(zl + i7 * DC + q4);
        a0.x += v0.x*m0 + v1.x*m1 + v2.x*m2 + v3.x*m3 + v4.x*m4 + v5.x*m5 + v6.x*m6 + v7.x*m7;
        a0.y += v0.y*m0 + v1.y*m1 + v2.y*m2 + v3.y*m3 + v4.y*m4 + v5.y*m5 + v6.y*m6 + v7.y*m7;
        a0.z += v0.z*m0 + v1.z*m1 + v2.z*m2 + v3.z*m3 + v4.z*m4 + v5.z*m5 + v6.z*m6 + v7.z*m7;
        a0.w += v0.w*m0 + v1.w*m1 + v2.w*m2 + v3.w*m3 + v4.w*m4 + v5.w*m5 + v6.w*m6 + v7.w*m7;
    }

    float inv = 1.0f / fmaxf((float)len, 1.0f);
    float4 r  = *(const float4*)(zr + t * 4);       // == zr + n*8 + q*4
    float4 bb = *(const float4*)(b2 + q4);
    float4 o;
    o.x = a0.x * inv + bb.x + r.x;
    o.y = a0.y * inv + bb.y + r.y;
    o.z = a0.z * inv + bb.z + r.z;
    o.w = a0.w * inv + bb.w + r.w;
    *(float4*)(out + t * 4) = o;
}

extern "C" void kernel_launch(void* const* d_in, const int* in_sizes, int n_in,
                              void* d_out, int out_size, void* d_ws, size_t ws_size,
                              hipStream_t stream)
{
    const float* x   = (const float*)d_in[0];
    const int*   ei  = (const int*)d_in[1];
    const float* W1l = (const float*)d_in[2];
    const float* b1  = (const float*)d_in[3];
    const float* W1r = (const float*)d_in[4];
    const float* W2l = (const float*)d_in[5];
    const float* b2  = (const float*)d_in[6];
    const float* W2r = (const float*)d_in[7];
    float* out = (float*)d_out;

    const int* src = ei;
    const int* dst = ei + NE;

    // ---- workspace layout (floats first, 16B-aligned throughout) ----
    float* xl = (float*)d_ws;                      // NN*16
    float* xr = xl + (size_t)NN * DH;              // NN*16
    float* zl = xr + (size_t)NN * DH;              // NN*8
    float* zr = zl + (size_t)NN * DC;              // NN*8
    int* cnt  = (int*)(zr + (size_t)NN * DC);      // NN
    int* ell  = cnt + NN;                          // NN*CAP
    // total ~22.6 MB

    k_gemm1   <<<NB, 256, 0, stream>>>(x, W1l, W1r, xl, xr, cnt);
    k_fill_ell<<<(NE / 2 + 255) / 256, 256, 0, stream>>>(src, dst, cnt, ell);
    k_l1      <<<(NN * 4 + 255) / 256, 256, 0, stream>>>(cnt, ell, xl, xr, b1, W2l, W2r, zl, zr);
    k_l2      <<<(NN * 2 + 255) / 256, 256, 0, stream>>>(cnt, ell, zl, zr, b2, out);
}

// Round 10
// 72.776 us; speedup vs baseline: 2.5821x; 1.0632x over previous
//
#include <hip/hip_runtime.h>

#define NN 50000
#define NE 600000
#define DI 128
#define DH 16
#define DC 8
#define CAP 64     // ELL capacity; deg ~ Poisson(12), P(deg>64) < 1e-20

// ---------------- K0: xl = x @ W1l, xr = x @ W1r (+ zero cnt) ----------------
// 4 threads per node; thread c computes output cols [c*8, c*8+8) over all 128 k.
__global__ __launch_bounds__(256) void k_gemm1(
    const float* __restrict__ x,
    const float* __restrict__ W1l,
    const float* __restrict__ W1r,
    float* __restrict__ xl,
    float* __restrict__ xr,
    int* __restrict__ cnt)
{
    int t = blockIdx.x * 256 + threadIdx.x;
    if (t < NN) cnt[t] = 0;

    __shared__ float Wc[DI][32];   // [k][j]: j<16 -> W1l, j>=16 -> W1r
    for (int i = threadIdx.x; i < DI * DH; i += 256) {
        int k = i >> 4, j = i & 15;
        Wc[k][j]      = W1l[i];
        Wc[k][j + 16] = W1r[i];
    }
    __syncthreads();
    if (t >= NN * 4) return;
    int n = t >> 2, c = t & 3;
    const int co = c * 8;

    float acc[8];
#pragma unroll
    for (int j = 0; j < 8; ++j) acc[j] = 0.f;

    const float4* xrow = (const float4*)(x + (size_t)n * DI);
#pragma unroll 4
    for (int k4 = 0; k4 < DI / 4; ++k4) {
        float4 xv = xrow[k4];
#pragma unroll
        for (int kk = 0; kk < 4; ++kk) {
            const float* wr = &Wc[k4 * 4 + kk][co];
            float4 w0 = *(const float4*)(wr);
            float4 w1 = *(const float4*)(wr + 4);
            float xs = (&xv.x)[kk];            // kk compile-time (unrolled)
            acc[0] += xs * w0.x; acc[1] += xs * w0.y;
            acc[2] += xs * w0.z; acc[3] += xs * w0.w;
            acc[4] += xs * w1.x; acc[5] += xs * w1.y;
            acc[6] += xs * w1.z; acc[7] += xs * w1.w;
        }
    }
    // c=0: xl cols 0-7; c=1: xl 8-15; c=2: xr 0-7; c=3: xr 8-15
    float* o = (c < 2) ? (xl + (size_t)n * DH + c * 8)
                       : (xr + (size_t)n * DH + (c - 2) * 8);
    *(float4*)(o)     = make_float4(acc[0], acc[1], acc[2], acc[3]);
    *(float4*)(o + 4) = make_float4(acc[4], acc[5], acc[6], acc[7]);
}

// ---------------- K1: ELL fill, 4 edges/thread ----------------
__global__ __launch_bounds__(256) void k_fill_ell(
    const int* __restrict__ src, const int* __restrict__ dst,
    int* __restrict__ cnt, int* __restrict__ ell)
{
    int e = (blockIdx.x * 256 + threadIdx.x) * 4;
    if (e >= NE) return;
    int4 d4 = *(const int4*)(dst + e);
    int4 s4 = *(const int4*)(src + e);
    int p0 = atomicAdd(&cnt[d4.x], 1);
    int p1 = atomicAdd(&cnt[d4.y], 1);
    int p2 = atomicAdd(&cnt[d4.z], 1);
    int p3 = atomicAdd(&cnt[d4.w], 1);
    if (p0 < CAP) ell[(size_t)d4.x * CAP + p0] = s4.x;
    if (p1 < CAP) ell[(size_t)d4.y * CAP + p1] = s4.y;
    if (p2 < CAP) ell[(size_t)d4.z * CAP + p2] = s4.z;
    if (p3 < CAP) ell[(size_t)d4.w * CAP + p3] = s4.w;
}

// ---------------- K2: agg1 + relu + layer-2 GEMM; 8 threads/node ----------------
// sub = t&7: s = sub>>2 (neighbor parity), q = sub&3 (feature quad)
__global__ __launch_bounds__(256) void k_l1(
    const int* __restrict__ cnt, const int* __restrict__ ell,
    const float* __restrict__ xl, const float* __restrict__ xr,
    const float* __restrict__ b1,
    const float* __restrict__ W2l, const float* __restrict__ W2r,
    float* __restrict__ zl, float* __restrict__ zr)
{
    int t = blockIdx.x * 256 + threadIdx.x;
    if (t >= NN * 8) return;
    int n = t >> 3, sub = t & 7, s = sub >> 2, q = sub & 3;
    const int q4 = q * 4;

    int len = min(cnt[n], CAP);
    const int* lst = ell + (size_t)n * CAP;

    // parity-split gather: s handles slots j with j%2 == s
    float4 a0 = make_float4(0.f, 0.f, 0.f, 0.f);
    for (int j = 0; j < len; j += 8) {
        int4 sA = *(const int4*)(lst + j);       // slots j..j+3 (16B-aligned)
        int4 sB = *(const int4*)(lst + j + 4);   // slots j+4..j+7
        int k0 = j + s,     k1 = j + 2 + s, k2 = j + 4 + s, k3 = j + 6 + s;
        int i0 = (k0 < len) ? (s ? sA.y : sA.x) : 0;  float m0 = (k0 < len) ? 1.f : 0.f;
        int i1 = (k1 < len) ? (s ? sA.w : sA.z) : 0;  float m1 = (k1 < len) ? 1.f : 0.f;
        int i2 = (k2 < len) ? (s ? sB.y : sB.x) : 0;  float m2 = (k2 < len) ? 1.f : 0.f;
        int i3 = (k3 < len) ? (s ? sB.w : sB.z) : 0;  float m3 = (k3 < len) ? 1.f : 0.f;
        float4 v0 = *(const float4*)(xl + (size_t)i0 * DH + q4);
        float4 v1 = *(const float4*)(xl + (size_t)i1 * DH + q4);
        float4 v2 = *(const float4*)(xl + (size_t)i2 * DH + q4);
        float4 v3 = *(const float4*)(xl + (size_t)i3 * DH + q4);
        a0.x += v0.x*m0 + v1.x*m1 + v2.x*m2 + v3.x*m3;
        a0.y += v0.y*m0 + v1.y*m1 + v2.y*m2 + v3.y*m3;
        a0.z += v0.z*m0 + v1.z*m1 + v2.z*m2 + v3.z*m3;
        a0.w += v0.w*m0 + v1.w*m1 + v2.w*m2 + v3.w*m3;
    }
    // combine the two parity halves (lane sub ^ 4)
    a0.x += __shfl_xor(a0.x, 4, 64);
    a0.y += __shfl_xor(a0.y, 4, 64);
    a0.z += __shfl_xor(a0.z, 4, 64);
    a0.w += __shfl_xor(a0.w, 4, 64);

    float inv = 1.0f / fmaxf((float)len, 1.0f);
    float4 r  = *(const float4*)(xr + (size_t)n * DH + q4);
    float4 bb = *(const float4*)(b1 + q4);
    float4 hq;
    hq.x = fmaxf(a0.x * inv + bb.x + r.x, 0.f);
    hq.y = fmaxf(a0.y * inv + bb.y + r.y, 0.f);
    hq.z = fmaxf(a0.z * inv + bb.z + r.z, 0.f);
    hq.w = fmaxf(a0.w * inv + bb.w + r.w, 0.f);

    // exchange quads within the same-parity 4-lane set (xor 1, xor 2 keep s)
    float4 p1, p2, p3;
    p1.x = __shfl_xor(hq.x, 1, 64); p1.y = __shfl_xor(hq.y, 1, 64);
    p1.z = __shfl_xor(hq.z, 1, 64); p1.w = __shfl_xor(hq.w, 1, 64);
    p2.x = __shfl_xor(hq.x, 2, 64); p2.y = __shfl_xor(hq.y, 2, 64);
    p2.z = __shfl_xor(hq.z, 2, 64); p2.w = __shfl_xor(hq.w, 2, 64);
    p3.x = __shfl_xor(p1.x, 2, 64); p3.y = __shfl_xor(p1.y, 2, 64);
    p3.z = __shfl_xor(p1.z, 2, 64); p3.w = __shfl_xor(p1.w, 2, 64);
    float4 Q[4];
#pragma unroll
    for (int jq = 0; jq < 4; ++jq) {
        int d = jq ^ q;
        Q[jq] = (d == 0) ? hq : (d == 1) ? p1 : (d == 2) ? p2 : p3;
    }

    // layer-2 GEMM (both s compute redundantly; only s==0 stores)
    const float* Wbase = (q < 2) ? (W2l + q * 4) : (W2r + (q - 2) * 4);
    float4 acc = make_float4(0.f, 0.f, 0.f, 0.f);
#pragma unroll
    for (int k = 0; k < DH; ++k) {
        float hk = (k < 4) ? ((const float*)&Q[0])[k & 3]
                 : (k < 8) ? ((const float*)&Q[1])[k & 3]
                 : (k < 12) ? ((const float*)&Q[2])[k & 3]
                 : ((const float*)&Q[3])[k & 3];
        float4 wv = *(const float4*)(Wbase + k * 8);
        acc.x += hk * wv.x; acc.y += hk * wv.y;
        acc.z += hk * wv.z; acc.w += hk * wv.w;
    }
    if (s == 0) {
        float* dstp = (q < 2) ? (zl + (size_t)n * DC + q * 4)
                              : (zr + (size_t)n * DC + (q - 2) * 4);
        *(float4*)dstp = acc;
    }
}

// ---------------- K3: agg2 + b2 + zr -> out; 4 threads/node ----------------
// sub = t&3: s = sub>>1 (parity), q = sub&1 (feature quad)
__global__ __launch_bounds__(256) void k_l2(
    const int* __restrict__ cnt, const int* __restrict__ ell,
    const float* __restrict__ zl, const float* __restrict__ zr,
    const float* __restrict__ b2, float* __restrict__ out)
{
    int t = blockIdx.x * 256 + threadIdx.x;
    if (t >= NN * 4) return;
    int n = t >> 2, sub = t & 3, s = sub >> 1, q = sub & 1;
    const int q4 = q * 4;
    int len = min(cnt[n], CAP);
    const int* lst = ell + (size_t)n * CAP;

    float4 a0 = make_float4(0.f, 0.f, 0.f, 0.f);
    for (int j = 0; j < len; j += 8) {
        int4 sA = *(const int4*)(lst + j);
        int4 sB = *(const int4*)(lst + j + 4);
        int k0 = j + s,     k1 = j + 2 + s, k2 = j + 4 + s, k3 = j + 6 + s;
        int i0 = (k0 < len) ? (s ? sA.y : sA.x) : 0;  float m0 = (k0 < len) ? 1.f : 0.f;
        int i1 = (k1 < len) ? (s ? sA.w : sA.z) : 0;  float m1 = (k1 < len) ? 1.f : 0.f;
        int i2 = (k2 < len) ? (s ? sB.y : sB.x) : 0;  float m2 = (k2 < len) ? 1.f : 0.f;
        int i3 = (k3 < len) ? (s ? sB.w : sB.z) : 0;  float m3 = (k3 < len) ? 1.f : 0.f;
        float4 v0 = *(const float4*)(zl + (size_t)i0 * DC + q4);
        float4 v1 = *(const float4*)(zl + (size_t)i1 * DC + q4);
        float4 v2 = *(const float4*)(zl + (size_t)i2 * DC + q4);
        float4 v3 = *(const float4*)(zl + (size_t)i3 * DC + q4);
        a0.x += v0.x*m0 + v1.x*m1 + v2.x*m2 + v3.x*m3;
        a0.y += v0.y*m0 + v1.y*m1 + v2.y*m2 + v3.y*m3;
        a0.z += v0.z*m0 + v1.z*m1 + v2.z*m2 + v3.z*m3;
        a0.w += v0.w*m0 + v1.w*m1 + v2.w*m2 + v3.w*m3;
    }
    // combine parity halves (lane sub ^ 2)
    a0.x += __shfl_xor(a0.x, 2, 64);
    a0.y += __shfl_xor(a0.y, 2, 64);
    a0.z += __shfl_xor(a0.z, 2, 64);
    a0.w += __shfl_xor(a0.w, 2, 64);

    if (s == 0) {
        float inv = 1.0f / fmaxf((float)len, 1.0f);
        float4 r  = *(const float4*)(zr + (size_t)n * DC + q4);
        float4 bb = *(const float4*)(b2 + q4);
        float4 o;
        o.x = a0.x * inv + bb.x + r.x;
        o.y = a0.y * inv + bb.y + r.y;
        o.z = a0.z * inv + bb.z + r.z;
        o.w = a0.w * inv + bb.w + r.w;
        *(float4*)(out + (size_t)n * DC + q4) = o;
    }
}

extern "C" void kernel_launch(void* const* d_in, const int* in_sizes, int n_in,
                              void* d_out, int out_size, void* d_ws, size_t ws_size,
                              hipStream_t stream)
{
    const float* x   = (const float*)d_in[0];
    const int*   ei  = (const int*)d_in[1];
    const float* W1l = (const float*)d_in[2];
    const float* b1  = (const float*)d_in[3];
    const float* W1r = (const float*)d_in[4];
    const float* W2l = (const float*)d_in[5];
    const float* b2  = (const float*)d_in[6];
    const float* W2r = (const float*)d_in[7];
    float* out = (float*)d_out;

    const int* src = ei;
    const int* dst = ei + NE;

    // ---- workspace layout (floats first, 16B-aligned throughout) ----
    float* xl = (float*)d_ws;                      // NN*16
    float* xr = xl + (size_t)NN * DH;              // NN*16
    float* zl = xr + (size_t)NN * DH;              // NN*8
    float* zr = zl + (size_t)NN * DC;              // NN*8
    int* cnt  = (int*)(zr + (size_t)NN * DC);      // NN
    int* ell  = cnt + NN;                          // NN*CAP
    // total ~22.6 MB

    k_gemm1   <<<(NN * 4 + 255) / 256, 256, 0, stream>>>(x, W1l, W1r, xl, xr, cnt);
    k_fill_ell<<<(NE / 4 + 255) / 256, 256, 0, stream>>>(src, dst, cnt, ell);
    k_l1      <<<(NN * 8 + 255) / 256, 256, 0, stream>>>(cnt, ell, xl, xr, b1, W2l, W2r, zl, zr);
    k_l2      <<<(NN * 4 + 255) / 256, 256, 0, stream>>>(cnt, ell, zl, zr, b2, out);
}